// Round 2
// baseline (33825.842 us; speedup 1.0000x reference)
//
#include <hip/hip_runtime.h>
#include <stdint.h>

#define B_ 64
#define T_ 1024
#define E_ 256
#define H_ 512
#define BH_ (B_*H_)          // 32768
#define DEC_ELEMS ((size_t)B_*512*1024)

typedef __attribute__((ext_vector_type(8))) short bf16x8;
typedef __attribute__((ext_vector_type(4))) float f32x4;

__device__ __forceinline__ unsigned short f2bf(float f) {
  union { float f; unsigned int u; } v; v.f = f;
  unsigned int r = (v.u + 0x7fffu + ((v.u >> 16) & 1u)) >> 16;
  return (unsigned short)r;
}
__device__ __forceinline__ float bf2f(unsigned short s) {
  union { float f; unsigned int u; } v; v.u = ((unsigned int)s) << 16;
  return v.f;
}
__device__ __forceinline__ float sigf(float x) { return 1.f/(1.f + __expf(-x)); }
__device__ __forceinline__ float tanhfast(float x) {
  float e = __expf(2.f*x);
  return 1.f - 2.f/(e + 1.f);      // saturates correctly at +-1 for |x| large
}
__device__ __forceinline__ void st4bf(unsigned short* p, float4 v) {
  ushort4 u; u.x=f2bf(v.x); u.y=f2bf(v.y); u.z=f2bf(v.z); u.w=f2bf(v.w);
  *(ushort4*)p = u;
}

// ---------------- prep: fp32 -> bf16 weight copies for the parallel GEMMs ----
__global__ void k_prep(const float* __restrict__ Wenc, const float* __restrict__ Wlin,
                       const float* __restrict__ Wdec,
                       unsigned short* __restrict__ wencb, unsigned short* __restrict__ wlinb,
                       unsigned short* __restrict__ wdecb) {
  int i = blockIdx.x*256 + threadIdx.x;      // 131072 each
  if (i < 131072) {
    wencb[i] = f2bf(Wenc[i]);
    wlinb[i] = f2bf(Wlin[i]);
    wdecb[i] = f2bf(Wdec[i]);
  }
}

// ---------------- encoder GEMM + LayerNorm -> enc_norm(bf16), encoded(bf16) --
// per block: one b, 16 t rows. D[t16 x o256] = x[b,:,t]^T @ Wenc^T
__global__ __launch_bounds__(256) void k_enc(const float* __restrict__ x,
    const unsigned short* __restrict__ wencb, const float* __restrict__ lng,
    const float* __restrict__ lnb,
    unsigned short* __restrict__ enc_norm, unsigned short* __restrict__ encoded) {
  __shared__ __align__(16) unsigned short xs[16][520]; // bf16 [t][c], 260dw stride == 4 mod 32
  __shared__ __align__(16) float es[16][265];          // fp32 [t][o]
  const int bx = blockIdx.x;
  const int b = bx >> 6, tt = (bx & 63) << 4;
  const int tid = threadIdx.x;

  const float* xb = x + (size_t)b*512*1024 + tt;
  #pragma unroll
  for (int it = 0; it < 8; ++it) {
    int idx = tid + it*256;                  // 0..2047: c=idx>>2, quarter i4
    int c = idx >> 2, i4 = idx & 3;
    float4 v = *(const float4*)(xb + (size_t)c*1024 + i4*4);
    xs[i4*4+0][c]=f2bf(v.x); xs[i4*4+1][c]=f2bf(v.y);
    xs[i4*4+2][c]=f2bf(v.z); xs[i4*4+3][c]=f2bf(v.w);
  }
  __syncthreads();

  const int w = tid >> 6, lane = tid & 63;
  const int n16 = lane & 15, q = lane >> 4;
  f32x4 acc[4];
  #pragma unroll
  for (int i = 0; i < 4; ++i) acc[i] = (f32x4){0.f,0.f,0.f,0.f};
  for (int ks = 0; ks < 16; ++ks) {
    int k0 = ks*32 + q*8;
    bf16x8 af = *(const bf16x8*)&xs[n16][k0];
    #pragma unroll
    for (int i = 0; i < 4; ++i) {
      int o = (w*4+i)*16 + n16;
      bf16x8 bf = *(const bf16x8*)&wencb[(size_t)o*512 + k0];
      acc[i] = __builtin_amdgcn_mfma_f32_16x16x32_bf16(af, bf, acc[i], 0,0,0);
    }
  }
  #pragma unroll
  for (int i = 0; i < 4; ++i) {
    int o = (w*4+i)*16 + n16;
    #pragma unroll
    for (int r = 0; r < 4; ++r) es[q*4+r][o] = acc[i][r];
  }
  __syncthreads();

  const int tl = tid >> 4, l16 = tid & 15;
  float s = 0.f, ss = 0.f;
  #pragma unroll
  for (int k = 0; k < 16; ++k) { float v = es[tl][l16 + 16*k]; s += v; ss += v*v; }
  #pragma unroll
  for (int d = 1; d < 16; d <<= 1) { s += __shfl_xor(s, d, 64); ss += __shfl_xor(ss, d, 64); }
  float mu  = s  * (1.f/256.f);
  float var = ss * (1.f/256.f) - mu*mu;
  float rstd = rsqrtf(var + 1e-5f);
  #pragma unroll
  for (int k = 0; k < 16; ++k) {
    int o = l16 + 16*k;
    xs[tl][o] = f2bf((es[tl][o] - mu)*rstd*lng[o] + lnb[o]);
  }
  __syncthreads();
  #pragma unroll
  for (int it = 0; it < 2; ++it) {
    int idx = tid + it*256; int row = idx >> 5, ch = idx & 31;
    *(uint4*)&enc_norm[((size_t)(b*1024 + tt + row))*256 + ch*8] = *(const uint4*)&xs[row][ch*8];
  }
  __syncthreads();
  #pragma unroll
  for (int k = 0; k < 16; ++k) { int o = l16 + 16*k; xs[tl][o] = f2bf(es[tl][o]); }
  __syncthreads();
  #pragma unroll
  for (int it = 0; it < 2; ++it) {
    int idx = tid + it*256; int row = idx >> 5, ch = idx & 31;
    *(uint4*)&encoded[((size_t)(b*1024 + tt + row))*256 + ch*8] = *(const uint4*)&xs[row][ch*8];
  }
}

// ---------------- persistent 2-layer LSTM recurrence ------------------------
__device__ __forceinline__ void sync_group(int* c, int target) {
  __syncthreads();
  if (threadIdx.x == 0) {
    __threadfence();
    __hip_atomic_fetch_add(c, 1, __ATOMIC_RELEASE, __HIP_MEMORY_SCOPE_AGENT);
    while (__hip_atomic_load(c, __ATOMIC_ACQUIRE, __HIP_MEMORY_SCOPE_AGENT) < target)
      __builtin_amdgcn_s_sleep(1);
  }
  __syncthreads();
}

// grid = 256 blocks x 256 threads. block = (g = bIdx&3 -> batch rows g*16..+16,
// j = bIdx>>2 -> h columns j*8..+8 i.e. 32 gate rows {q*512 + j*8 + 0..7}).
__global__ __launch_bounds__(256, 1) void k_recur(
    const float* __restrict__ states,
    const float* __restrict__ Wih1, const float* __restrict__ Whh1,
    const float* __restrict__ bih1, const float* __restrict__ bhh1,
    const float* __restrict__ Wih2, const float* __restrict__ Whh2,
    const float* __restrict__ bih2, const float* __restrict__ bhh2,
    const unsigned short* __restrict__ enc_norm,
    unsigned short* __restrict__ x2,
    unsigned short* __restrict__ h1bc, unsigned short* __restrict__ h2bc, // [2][B][H] bf16
    int* cnt1, int* cnt2,                                                 // [4][T]
    float* __restrict__ out_states)                                       // [4][B][H]
{
  __shared__ __align__(16) unsigned short wl1[32][776];  // [n][ 0:256 Wih1 | 256:768 Whh1 ]
  __shared__ __align__(16) unsigned short wl2[32][1032]; // [n][ 0:512 Wih2 | 512:1024 Whh2 ]
  __shared__ __align__(16) unsigned short inA[16][1032]; // staged input rows (batch-major)
  __shared__ float psum[2][16][16];
  __shared__ float gbuf[32][17];
  __shared__ float cb[2][8][16];             // c state [layer][hc][b]
  __shared__ float bias1[32], bias2[32];

  const int tid = threadIdx.x;
  const int g  = blockIdx.x & 3;
  const int j  = blockIdx.x >> 2;
  const int b0 = g*16;
  const int hc0 = j*8;

  // --- load weight slices to LDS (fp32 -> bf16) ---
  for (int idx = tid; idx < 32*192; idx += 256) {
    int n = idx / 192, p = idx % 192;
    int R = (n>>3)*512 + hc0 + (n&7);
    if (p < 64) {
      st4bf(&wl1[n][p*4], *(const float4*)(Wih1 + (size_t)R*256 + p*4));
    } else {
      int p2 = p - 64;
      st4bf(&wl1[n][256 + p2*4], *(const float4*)(Whh1 + (size_t)R*512 + p2*4));
    }
  }
  for (int idx = tid; idx < 32*256; idx += 256) {
    int n = idx >> 8, p = idx & 255;
    int R = (n>>3)*512 + hc0 + (n&7);
    if (p < 128) {
      st4bf(&wl2[n][p*4], *(const float4*)(Wih2 + (size_t)R*512 + p*4));
    } else {
      int p2 = p - 128;
      st4bf(&wl2[n][512 + p2*4], *(const float4*)(Whh2 + (size_t)R*512 + p2*4));
    }
  }
  if (tid < 32) {
    int R = (tid>>3)*512 + hc0 + (tid&7);
    bias1[tid] = bih1[R] + bhh1[R];
    bias2[tid] = bih2[R] + bhh2[R];
  }
  if (tid < 128) {
    int b = tid & 15, hc = tid >> 4;
    cb[0][hc][b] = states[(size_t)1*BH_ + (b0+b)*H_ + hc0+hc];
    cb[1][hc][b] = states[(size_t)3*BH_ + (b0+b)*H_ + hc0+hc];
  }
  // every wg writes the FULL parity-1 init buffers (identical values -> race-free)
  for (int idx = tid; idx < BH_; idx += 256) {
    h1bc[BH_ + idx] = f2bf(states[idx]);
    h2bc[BH_ + idx] = f2bf(states[(size_t)2*BH_ + idx]);
  }
  __syncthreads();

  const int w = tid >> 6, lane = tid & 63;
  const int n16 = lane & 15, q = lane >> 4;
  const int nt = w & 1, kh = w >> 1;

  for (int t = 0; t < T_; ++t) {
    const int pc = t & 1, pp = pc ^ 1;

    // ---- stage L1 input: [enc_norm(t) 0:256 | h1(t-1) 256:768]
    for (int idx = tid; idx < 16*32; idx += 256) {
      int b = idx >> 5, p = idx & 31;
      *(uint4*)&inA[b][p*8] = *(const uint4*)&enc_norm[((size_t)(b0+b)*T_ + t)*E_ + p*8];
    }
    for (int idx = tid; idx < 16*64; idx += 256) {
      int b = idx >> 6, p = idx & 63;
      *(uint4*)&inA[b][256 + p*8] = *(const uint4*)&h1bc[(size_t)pp*BH_ + (b0+b)*H_ + p*8];
    }
    __syncthreads();

    { // L1 gates: K=768, 2-way K split across waves
      f32x4 acc = (f32x4){0.f,0.f,0.f,0.f};
      #pragma unroll
      for (int ks = 0; ks < 12; ++ks) {
        int k0 = kh*384 + ks*32 + q*8;
        bf16x8 af = *(const bf16x8*)&inA[n16][k0];
        bf16x8 bf = *(const bf16x8*)&wl1[nt*16 + n16][k0];
        acc = __builtin_amdgcn_mfma_f32_16x16x32_bf16(af, bf, acc, 0,0,0);
      }
      if (kh == 1) {
        for (int r = 0; r < 4; ++r) psum[nt][n16][q*4+r] = acc[r];
      }
      __syncthreads();
      if (kh == 0) {
        for (int r = 0; r < 4; ++r) gbuf[nt*16+n16][q*4+r] = acc[r] + psum[nt][n16][q*4+r];
      }
      __syncthreads();
    }
    if (tid < 128) {
      int b = tid & 15, hc = tid >> 4;
      float ip = gbuf[hc][b]    + bias1[hc];
      float fp = gbuf[8+hc][b]  + bias1[8+hc];
      float gp = gbuf[16+hc][b] + bias1[16+hc];
      float op = gbuf[24+hc][b] + bias1[24+hc];
      float c = sigf(fp)*cb[0][hc][b] + sigf(ip)*tanhfast(gp);
      cb[0][hc][b] = c;
      float h = sigf(op)*tanhfast(c);
      h1bc[(size_t)pc*BH_ + (b0+b)*H_ + hc0+hc] = f2bf(h);
      if (t == T_-1) {
        out_states[(size_t)0*BH_ + (b0+b)*H_ + hc0+hc] = h;
        out_states[(size_t)1*BH_ + (b0+b)*H_ + hc0+hc] = c;
      }
    }
    sync_group(&cnt1[g*T_ + t], 64);

    // ---- stage L2 input: [x1(t)=h1(t) 0:512 | h2(t-1) 512:1024]
    for (int idx = tid; idx < 16*64; idx += 256) {
      int b = idx >> 6, p = idx & 63;
      *(uint4*)&inA[b][p*8]       = *(const uint4*)&h1bc[(size_t)pc*BH_ + (b0+b)*H_ + p*8];
      *(uint4*)&inA[b][512 + p*8] = *(const uint4*)&h2bc[(size_t)pp*BH_ + (b0+b)*H_ + p*8];
    }
    __syncthreads();

    { // L2 gates: K=1024
      f32x4 acc = (f32x4){0.f,0.f,0.f,0.f};
      #pragma unroll
      for (int ks = 0; ks < 16; ++ks) {
        int k0 = kh*512 + ks*32 + q*8;
        bf16x8 af = *(const bf16x8*)&inA[n16][k0];
        bf16x8 bf = *(const bf16x8*)&wl2[nt*16 + n16][k0];
        acc = __builtin_amdgcn_mfma_f32_16x16x32_bf16(af, bf, acc, 0,0,0);
      }
      if (kh == 1) {
        for (int r = 0; r < 4; ++r) psum[nt][n16][q*4+r] = acc[r];
      }
      __syncthreads();
      if (kh == 0) {
        for (int r = 0; r < 4; ++r) gbuf[nt*16+n16][q*4+r] = acc[r] + psum[nt][n16][q*4+r];
      }
      __syncthreads();
    }
    if (tid < 128) {
      int b = tid & 15, hc = tid >> 4;
      float ip = gbuf[hc][b]    + bias2[hc];
      float fp = gbuf[8+hc][b]  + bias2[8+hc];
      float gp = gbuf[16+hc][b] + bias2[16+hc];
      float op = gbuf[24+hc][b] + bias2[24+hc];
      float c = sigf(fp)*cb[1][hc][b] + sigf(ip)*tanhfast(gp);
      cb[1][hc][b] = c;
      float h = sigf(op)*tanhfast(c);
      unsigned short hb = f2bf(h);
      h2bc[(size_t)pc*BH_ + (b0+b)*H_ + hc0+hc] = hb;
      x2[((size_t)(b0+b)*T_ + t)*H_ + hc0+hc] = hb;
      if (t == T_-1) {
        out_states[(size_t)2*BH_ + (b0+b)*H_ + hc0+hc] = h;
        out_states[(size_t)3*BH_ + (b0+b)*H_ + hc0+hc] = c;
      }
    }
    sync_group(&cnt2[g*T_ + t], 64);
  }
}

// ---------------- mask GEMM + apply to encoded (in place -> est) ------------
__global__ __launch_bounds__(256) void k_mask(const unsigned short* __restrict__ x2,
    const unsigned short* __restrict__ wlinb, const float* __restrict__ blin,
    unsigned short* __restrict__ est) {
  const int bx = blockIdx.x;
  const int b = bx >> 6, tt = (bx & 63) << 4;
  const int tid = threadIdx.x, w = tid >> 6, lane = tid & 63;
  const int n16 = lane & 15, q = lane >> 4;
  f32x4 acc[4];
  #pragma unroll
  for (int i = 0; i < 4; ++i) acc[i] = (f32x4){0.f,0.f,0.f,0.f};
  const unsigned short* arow = x2 + ((size_t)b*1024 + tt)*512;
  for (int ks = 0; ks < 16; ++ks) {
    int k0 = ks*32 + q*8;
    bf16x8 af = *(const bf16x8*)&arow[(size_t)n16*512 + k0];
    #pragma unroll
    for (int i = 0; i < 4; ++i) {
      int o = (w*4+i)*16 + n16;
      bf16x8 bf = *(const bf16x8*)&wlinb[(size_t)o*512 + k0];
      acc[i] = __builtin_amdgcn_mfma_f32_16x16x32_bf16(af, bf, acc[i], 0,0,0);
    }
  }
  #pragma unroll
  for (int i = 0; i < 4; ++i) {
    int o = (w*4+i)*16 + n16;
    float bl = blin[o];
    #pragma unroll
    for (int r = 0; r < 4; ++r) {
      size_t p = ((size_t)b*1024 + tt + q*4 + r)*256 + o;
      float m = sigf(acc[i][r] + bl);
      est[p] = f2bf(m * bf2f(est[p]));
    }
  }
}

// ---------------- decoder GEMM: dec[b,f,t] = sum_o est[b,t,o] Wdec[f,o] -----
__global__ __launch_bounds__(256) void k_dec(const unsigned short* __restrict__ est,
    const unsigned short* __restrict__ wdecb, float* __restrict__ dec) {
  const int bx = blockIdx.x;                   // 64 * 8 * 16
  const int b = bx >> 7, rem = bx & 127, fy = rem >> 4, tx = rem & 15;
  const int f0 = fy*64, t0 = tx*64;
  const int tid = threadIdx.x, w = tid >> 6, lane = tid & 63;
  const int n16 = lane & 15, q = lane >> 4;
  f32x4 acc[4];
  #pragma unroll
  for (int i = 0; i < 4; ++i) acc[i] = (f32x4){0.f,0.f,0.f,0.f};
  const int fr = f0 + w*16 + n16;              // A row (f) for this lane
  for (int ks = 0; ks < 8; ++ks) {
    int k0 = ks*32 + q*8;
    bf16x8 af = *(const bf16x8*)&wdecb[(size_t)fr*256 + k0];
    #pragma unroll
    for (int i = 0; i < 4; ++i) {
      int trow = t0 + i*16 + n16;              // B col (t) for this lane
      bf16x8 bf = *(const bf16x8*)&est[((size_t)b*1024 + trow)*256 + k0];
      acc[i] = __builtin_amdgcn_mfma_f32_16x16x32_bf16(af, bf, acc[i], 0,0,0);
    }
  }
  #pragma unroll
  for (int i = 0; i < 4; ++i) {
    int tcol = t0 + i*16 + n16;
    #pragma unroll
    for (int r = 0; r < 4; ++r) {
      int f = f0 + w*16 + q*4 + r;
      dec[((size_t)b*512 + f)*1024 + tcol] = acc[i][r];
    }
  }
}

extern "C" void kernel_launch(void* const* d_in, const int* in_sizes, int n_in,
                              void* d_out, int out_size, void* d_ws, size_t ws_size,
                              hipStream_t stream) {
  (void)in_sizes; (void)n_in; (void)out_size; (void)ws_size;
  const float* x      = (const float*)d_in[0];
  const float* states = (const float*)d_in[1];
  const float* Wenc   = (const float*)d_in[2];
  const float* lng    = (const float*)d_in[3];
  const float* lnb    = (const float*)d_in[4];
  const float* Wih1   = (const float*)d_in[5];
  const float* Whh1   = (const float*)d_in[6];
  const float* bih1   = (const float*)d_in[7];
  const float* bhh1   = (const float*)d_in[8];
  const float* Wih2   = (const float*)d_in[9];
  const float* Whh2   = (const float*)d_in[10];
  const float* bih2   = (const float*)d_in[11];
  const float* bhh2   = (const float*)d_in[12];
  const float* Wlin   = (const float*)d_in[13];
  const float* blin   = (const float*)d_in[14];
  const float* Wdec   = (const float*)d_in[15];

  float* dec = (float*)d_out;
  float* out_states = dec + DEC_ELEMS;

  char* ws = (char*)d_ws;
  unsigned short* enc_norm = (unsigned short*)ws; ws += (size_t)B_*T_*E_*2;   // 32 MB
  unsigned short* encoded  = (unsigned short*)ws; ws += (size_t)B_*T_*E_*2;   // 32 MB (becomes est in place)
  unsigned short* x2buf    = (unsigned short*)ws; ws += (size_t)B_*T_*H_*2;   // 64 MB
  unsigned short* wencb    = (unsigned short*)ws; ws += 131072*2;
  unsigned short* wlinb    = (unsigned short*)ws; ws += 131072*2;
  unsigned short* wdecb    = (unsigned short*)ws; ws += 131072*2;
  unsigned short* h1bc     = (unsigned short*)ws; ws += 2*BH_*2;
  unsigned short* h2bc     = (unsigned short*)ws; ws += 2*BH_*2;
  int* cnts                = (int*)ws;            ws += 2*4*T_*4;

  (void)hipMemsetAsync(cnts, 0, 2*4*T_*4, stream);
  k_prep<<<512, 256, 0, stream>>>(Wenc, Wlin, Wdec, wencb, wlinb, wdecb);
  k_enc<<<4096, 256, 0, stream>>>(x, wencb, lng, lnb, enc_norm, encoded);
  k_recur<<<256, 256, 0, stream>>>(states, Wih1, Whh1, bih1, bhh1,
                                   Wih2, Whh2, bih2, bhh2,
                                   enc_norm, x2buf, h1bc, h2bc,
                                   cnts, cnts + 4*T_, out_states);
  k_mask<<<4096, 256, 0, stream>>>(x2buf, wlinb, blin, encoded);
  k_dec<<<8192, 256, 0, stream>>>(encoded, wdecb, dec);
}

// Round 3
// 8789.379 us; speedup vs baseline: 3.8485x; 3.8485x over previous
//
#include <hip/hip_runtime.h>
#include <stdint.h>

#define B_ 64
#define T_ 1024
#define E_ 256
#define H_ 512
#define BH_ (B_*H_)          // 32768
#define DEC_ELEMS ((size_t)B_*512*1024)

typedef __attribute__((ext_vector_type(8))) short bf16x8;
typedef __attribute__((ext_vector_type(4))) float f32x4;
typedef unsigned long long u64;

__device__ __forceinline__ unsigned short f2bf(float f) {
  union { float f; unsigned int u; } v; v.f = f;
  unsigned int r = (v.u + 0x7fffu + ((v.u >> 16) & 1u)) >> 16;
  return (unsigned short)r;
}
__device__ __forceinline__ float bf2f(unsigned short s) {
  union { float f; unsigned int u; } v; v.u = ((unsigned int)s) << 16;
  return v.f;
}
__device__ __forceinline__ float sigf(float x) { return 1.f/(1.f + __expf(-x)); }
__device__ __forceinline__ float tanhfast(float x) {
  float e = __expf(2.f*x);
  return 1.f - 2.f/(e + 1.f);
}
__device__ __forceinline__ void st4bf(unsigned short* p, float4 v) {
  ushort4 u; u.x=f2bf(v.x); u.y=f2bf(v.y); u.z=f2bf(v.z); u.w=f2bf(v.w);
  *(ushort4*)p = u;
}
// device-coherent (IF$-level) 8B access, NO cache-wide maintenance ops
__device__ __forceinline__ u64 ld_dc64(const unsigned short* p) {
  return __hip_atomic_load((const u64*)p, __ATOMIC_RELAXED, __HIP_MEMORY_SCOPE_AGENT);
}
__device__ __forceinline__ void st_dc64(unsigned short* p, u64 v) {
  __hip_atomic_store((u64*)p, v, __ATOMIC_RELAXED, __HIP_MEMORY_SCOPE_AGENT);
}

// ---------------- prep: fp32 -> bf16 weight copies for the parallel GEMMs ----
__global__ void k_prep(const float* __restrict__ Wenc, const float* __restrict__ Wlin,
                       const float* __restrict__ Wdec,
                       unsigned short* __restrict__ wencb, unsigned short* __restrict__ wlinb,
                       unsigned short* __restrict__ wdecb) {
  int i = blockIdx.x*256 + threadIdx.x;      // 131072 each
  if (i < 131072) {
    wencb[i] = f2bf(Wenc[i]);
    wlinb[i] = f2bf(Wlin[i]);
    wdecb[i] = f2bf(Wdec[i]);
  }
}

// ---------------- encoder GEMM + LayerNorm -> enc_norm(bf16), encoded(bf16) --
__global__ __launch_bounds__(256) void k_enc(const float* __restrict__ x,
    const unsigned short* __restrict__ wencb, const float* __restrict__ lng,
    const float* __restrict__ lnb,
    unsigned short* __restrict__ enc_norm, unsigned short* __restrict__ encoded) {
  __shared__ __align__(16) unsigned short xs[16][520];
  __shared__ __align__(16) float es[16][265];
  const int bx = blockIdx.x;
  const int b = bx >> 6, tt = (bx & 63) << 4;
  const int tid = threadIdx.x;

  const float* xb = x + (size_t)b*512*1024 + tt;
  #pragma unroll
  for (int it = 0; it < 8; ++it) {
    int idx = tid + it*256;
    int c = idx >> 2, i4 = idx & 3;
    float4 v = *(const float4*)(xb + (size_t)c*1024 + i4*4);
    xs[i4*4+0][c]=f2bf(v.x); xs[i4*4+1][c]=f2bf(v.y);
    xs[i4*4+2][c]=f2bf(v.z); xs[i4*4+3][c]=f2bf(v.w);
  }
  __syncthreads();

  const int w = tid >> 6, lane = tid & 63;
  const int n16 = lane & 15, q = lane >> 4;
  f32x4 acc[4];
  #pragma unroll
  for (int i = 0; i < 4; ++i) acc[i] = (f32x4){0.f,0.f,0.f,0.f};
  for (int ks = 0; ks < 16; ++ks) {
    int k0 = ks*32 + q*8;
    bf16x8 af = *(const bf16x8*)&xs[n16][k0];
    #pragma unroll
    for (int i = 0; i < 4; ++i) {
      int o = (w*4+i)*16 + n16;
      bf16x8 bf = *(const bf16x8*)&wencb[(size_t)o*512 + k0];
      acc[i] = __builtin_amdgcn_mfma_f32_16x16x32_bf16(af, bf, acc[i], 0,0,0);
    }
  }
  #pragma unroll
  for (int i = 0; i < 4; ++i) {
    int o = (w*4+i)*16 + n16;
    #pragma unroll
    for (int r = 0; r < 4; ++r) es[q*4+r][o] = acc[i][r];
  }
  __syncthreads();

  const int tl = tid >> 4, l16 = tid & 15;
  float s = 0.f, ss = 0.f;
  #pragma unroll
  for (int k = 0; k < 16; ++k) { float v = es[tl][l16 + 16*k]; s += v; ss += v*v; }
  #pragma unroll
  for (int d = 1; d < 16; d <<= 1) { s += __shfl_xor(s, d, 64); ss += __shfl_xor(ss, d, 64); }
  float mu  = s  * (1.f/256.f);
  float var = ss * (1.f/256.f) - mu*mu;
  float rstd = rsqrtf(var + 1e-5f);
  #pragma unroll
  for (int k = 0; k < 16; ++k) {
    int o = l16 + 16*k;
    xs[tl][o] = f2bf((es[tl][o] - mu)*rstd*lng[o] + lnb[o]);
  }
  __syncthreads();
  #pragma unroll
  for (int it = 0; it < 2; ++it) {
    int idx = tid + it*256; int row = idx >> 5, ch = idx & 31;
    *(uint4*)&enc_norm[((size_t)(b*1024 + tt + row))*256 + ch*8] = *(const uint4*)&xs[row][ch*8];
  }
  __syncthreads();
  #pragma unroll
  for (int k = 0; k < 16; ++k) { int o = l16 + 16*k; xs[tl][o] = f2bf(es[tl][o]); }
  __syncthreads();
  #pragma unroll
  for (int it = 0; it < 2; ++it) {
    int idx = tid + it*256; int row = idx >> 5, ch = idx & 31;
    *(uint4*)&encoded[((size_t)(b*1024 + tt + row))*256 + ch*8] = *(const uint4*)&xs[row][ch*8];
  }
}

// ---------------- persistent 2-layer LSTM recurrence ------------------------
// Relaxed agent-scope flag. Ordering: __syncthreads drains vmcnt (sc1 stores
// acked at IF$) before any thread reaches the flag add; data reads are sc1
// (IF$-direct), so no acquire/release fences (no buffer_wbl2/buffer_inv) needed.
__device__ __forceinline__ void publish_wait(int* c, int target) {
  __syncthreads();
  if (threadIdx.x == 0) {
    __hip_atomic_fetch_add(c, 1, __ATOMIC_RELAXED, __HIP_MEMORY_SCOPE_AGENT);
    while (__hip_atomic_load(c, __ATOMIC_RELAXED, __HIP_MEMORY_SCOPE_AGENT) < target)
      __builtin_amdgcn_s_sleep(2);
  }
  __syncthreads();
}

// grid = 256 blocks x 256 threads. g = bIdx&3 -> batch rows g*16..+16,
// j = bIdx>>2 -> h cols j*8..+8 (32 gate rows {q*512 + j*8 + 0..7}).
__global__ __launch_bounds__(256, 1) void k_recur(
    const float* __restrict__ states,
    const float* __restrict__ Wih1, const float* __restrict__ Whh1,
    const float* __restrict__ bih1, const float* __restrict__ bhh1,
    const float* __restrict__ Wih2, const float* __restrict__ Whh2,
    const float* __restrict__ bih2, const float* __restrict__ bhh2,
    const unsigned short* __restrict__ enc_norm,
    unsigned short* __restrict__ x2,
    unsigned short* h1bc, unsigned short* h2bc,                  // [2][B][H] bf16
    int* cnt1, int* cnt2,                                        // [4][T]
    float* __restrict__ out_states)                              // [4][B][H]
{
  __shared__ __align__(16) unsigned short wl1[32][776];
  __shared__ __align__(16) unsigned short wl2[32][1032];
  __shared__ __align__(16) unsigned short inA[16][1032];
  __shared__ float psum[2][16][16];
  __shared__ float gbuf[32][17];
  __shared__ float cb[2][8][16];
  __shared__ float bias1[32], bias2[32];
  __shared__ __align__(8) unsigned short h1sh[16][8], h2sh[16][8];

  const int tid = threadIdx.x;
  const int g  = blockIdx.x & 3;
  const int j  = blockIdx.x >> 2;
  const int b0 = g*16;
  const int hc0 = j*8;

  // --- load weight slices to LDS (fp32 -> bf16) ---
  for (int idx = tid; idx < 32*192; idx += 256) {
    int n = idx / 192, p = idx % 192;
    int R = (n>>3)*512 + hc0 + (n&7);
    if (p < 64) {
      st4bf(&wl1[n][p*4], *(const float4*)(Wih1 + (size_t)R*256 + p*4));
    } else {
      int p2 = p - 64;
      st4bf(&wl1[n][256 + p2*4], *(const float4*)(Whh1 + (size_t)R*512 + p2*4));
    }
  }
  for (int idx = tid; idx < 32*256; idx += 256) {
    int n = idx >> 8, p = idx & 255;
    int R = (n>>3)*512 + hc0 + (n&7);
    if (p < 128) {
      st4bf(&wl2[n][p*4], *(const float4*)(Wih2 + (size_t)R*512 + p*4));
    } else {
      int p2 = p - 128;
      st4bf(&wl2[n][512 + p2*4], *(const float4*)(Whh2 + (size_t)R*512 + p2*4));
    }
  }
  if (tid < 32) {
    int R = (tid>>3)*512 + hc0 + (tid&7);
    bias1[tid] = bih1[R] + bhh1[R];
    bias2[tid] = bih2[R] + bhh2[R];
  }
  if (tid < 128) {
    int b = tid & 15, hc = tid >> 4;
    cb[0][hc][b] = states[(size_t)1*BH_ + (b0+b)*H_ + hc0+hc];
    cb[1][hc][b] = states[(size_t)3*BH_ + (b0+b)*H_ + hc0+hc];
  }
  // every wg writes the FULL parity-1 init buffers (identical values, sc1 stores)
  for (int idx = tid; idx < BH_/4; idx += 256) {
    float4 a  = *(const float4*)(states + (size_t)idx*4);
    float4 b2 = *(const float4*)(states + (size_t)2*BH_ + idx*4);
    ushort4 ua; ua.x=f2bf(a.x);  ua.y=f2bf(a.y);  ua.z=f2bf(a.z);  ua.w=f2bf(a.w);
    ushort4 ub; ub.x=f2bf(b2.x); ub.y=f2bf(b2.y); ub.z=f2bf(b2.z); ub.w=f2bf(b2.w);
    st_dc64(&h1bc[BH_ + idx*4], *(const u64*)&ua);
    st_dc64(&h2bc[BH_ + idx*4], *(const u64*)&ub);
  }
  __syncthreads();

  const int w = tid >> 6, lane = tid & 63;
  const int n16 = lane & 15, q = lane >> 4;
  const int nt = w & 1, kh = w >> 1;

  for (int t = 0; t < T_; ++t) {
    const int pc = t & 1, pp = pc ^ 1;

    // ---- stage L1 input: [enc_norm(t) 0:256 | h1(t-1) 256:768]
    for (int idx = tid; idx < 16*32; idx += 256) {
      int b = idx >> 5, p = idx & 31;
      *(uint4*)&inA[b][p*8] = *(const uint4*)&enc_norm[((size_t)(b0+b)*T_ + t)*E_ + p*8];
    }
    for (int idx = tid; idx < 16*128; idx += 256) {
      int b = idx >> 7, p = idx & 127;
      u64 v = ld_dc64(&h1bc[(size_t)pp*BH_ + (b0+b)*H_ + p*4]);
      *(u64*)&inA[b][256 + p*4] = v;
    }
    __syncthreads();

    { // L1 gates: K=768, 2-way K split across waves
      f32x4 acc = (f32x4){0.f,0.f,0.f,0.f};
      #pragma unroll
      for (int ks = 0; ks < 12; ++ks) {
        int k0 = kh*384 + ks*32 + q*8;
        bf16x8 af = *(const bf16x8*)&inA[n16][k0];
        bf16x8 bf = *(const bf16x8*)&wl1[nt*16 + n16][k0];
        acc = __builtin_amdgcn_mfma_f32_16x16x32_bf16(af, bf, acc, 0,0,0);
      }
      if (kh == 1) {
        for (int r = 0; r < 4; ++r) psum[nt][n16][q*4+r] = acc[r];
      }
      __syncthreads();
      if (kh == 0) {
        for (int r = 0; r < 4; ++r) gbuf[nt*16+n16][q*4+r] = acc[r] + psum[nt][n16][q*4+r];
      }
      __syncthreads();
    }
    if (tid < 128) {
      int b = tid & 15, hc = tid >> 4;
      float ip = gbuf[hc][b]    + bias1[hc];
      float fp = gbuf[8+hc][b]  + bias1[8+hc];
      float gp = gbuf[16+hc][b] + bias1[16+hc];
      float op = gbuf[24+hc][b] + bias1[24+hc];
      float c = sigf(fp)*cb[0][hc][b] + sigf(ip)*tanhfast(gp);
      cb[0][hc][b] = c;
      float h = sigf(op)*tanhfast(c);
      h1sh[b][hc] = f2bf(h);
      if (t == T_-1) {
        out_states[(size_t)0*BH_ + (b0+b)*H_ + hc0+hc] = h;
        out_states[(size_t)1*BH_ + (b0+b)*H_ + hc0+hc] = c;
      }
    }
    __syncthreads();
    if (tid < 32) {
      int b = tid & 15, qq = tid >> 4;
      u64 v = *(const u64*)&h1sh[b][qq*4];
      st_dc64(&h1bc[(size_t)pc*BH_ + (b0+b)*H_ + hc0 + qq*4], v);
    }
    publish_wait(&cnt1[g*T_ + t], 64);

    // ---- stage L2 input: [x1(t)=h1(t) 0:512 | h2(t-1) 512:1024]
    for (int idx = tid; idx < 16*128; idx += 256) {
      int b = idx >> 7, p = idx & 127;
      u64 v1 = ld_dc64(&h1bc[(size_t)pc*BH_ + (b0+b)*H_ + p*4]);
      u64 v2 = ld_dc64(&h2bc[(size_t)pp*BH_ + (b0+b)*H_ + p*4]);
      *(u64*)&inA[b][p*4]       = v1;
      *(u64*)&inA[b][512 + p*4] = v2;
    }
    __syncthreads();

    { // L2 gates: K=1024
      f32x4 acc = (f32x4){0.f,0.f,0.f,0.f};
      #pragma unroll
      for (int ks = 0; ks < 16; ++ks) {
        int k0 = kh*512 + ks*32 + q*8;
        bf16x8 af = *(const bf16x8*)&inA[n16][k0];
        bf16x8 bf = *(const bf16x8*)&wl2[nt*16 + n16][k0];
        acc = __builtin_amdgcn_mfma_f32_16x16x32_bf16(af, bf, acc, 0,0,0);
      }
      if (kh == 1) {
        for (int r = 0; r < 4; ++r) psum[nt][n16][q*4+r] = acc[r];
      }
      __syncthreads();
      if (kh == 0) {
        for (int r = 0; r < 4; ++r) gbuf[nt*16+n16][q*4+r] = acc[r] + psum[nt][n16][q*4+r];
      }
      __syncthreads();
    }
    if (tid < 128) {
      int b = tid & 15, hc = tid >> 4;
      float ip = gbuf[hc][b]    + bias2[hc];
      float fp = gbuf[8+hc][b]  + bias2[8+hc];
      float gp = gbuf[16+hc][b] + bias2[16+hc];
      float op = gbuf[24+hc][b] + bias2[24+hc];
      float c = sigf(fp)*cb[1][hc][b] + sigf(ip)*tanhfast(gp);
      cb[1][hc][b] = c;
      float h = sigf(op)*tanhfast(c);
      h2sh[b][hc] = f2bf(h);
      if (t == T_-1) {
        out_states[(size_t)2*BH_ + (b0+b)*H_ + hc0+hc] = h;
        out_states[(size_t)3*BH_ + (b0+b)*H_ + hc0+hc] = c;
      }
    }
    __syncthreads();
    if (tid < 32) {
      int b = tid & 15, qq = tid >> 4;
      u64 v = *(const u64*)&h2sh[b][qq*4];
      st_dc64(&h2bc[(size_t)pc*BH_ + (b0+b)*H_ + hc0 + qq*4], v);
      *(u64*)&x2[((size_t)(b0+b)*T_ + t)*H_ + hc0 + qq*4] = v;
    }
    publish_wait(&cnt2[g*T_ + t], 64);
  }
}

// ---------------- mask GEMM + apply to encoded (in place -> est) ------------
__global__ __launch_bounds__(256) void k_mask(const unsigned short* __restrict__ x2,
    const unsigned short* __restrict__ wlinb, const float* __restrict__ blin,
    unsigned short* __restrict__ est) {
  const int bx = blockIdx.x;
  const int b = bx >> 6, tt = (bx & 63) << 4;
  const int tid = threadIdx.x, w = tid >> 6, lane = tid & 63;
  const int n16 = lane & 15, q = lane >> 4;
  f32x4 acc[4];
  #pragma unroll
  for (int i = 0; i < 4; ++i) acc[i] = (f32x4){0.f,0.f,0.f,0.f};
  const unsigned short* arow = x2 + ((size_t)b*1024 + tt)*512;
  for (int ks = 0; ks < 16; ++ks) {
    int k0 = ks*32 + q*8;
    bf16x8 af = *(const bf16x8*)&arow[(size_t)n16*512 + k0];
    #pragma unroll
    for (int i = 0; i < 4; ++i) {
      int o = (w*4+i)*16 + n16;
      bf16x8 bf = *(const bf16x8*)&wlinb[(size_t)o*512 + k0];
      acc[i] = __builtin_amdgcn_mfma_f32_16x16x32_bf16(af, bf, acc[i], 0,0,0);
    }
  }
  #pragma unroll
  for (int i = 0; i < 4; ++i) {
    int o = (w*4+i)*16 + n16;
    float bl = blin[o];
    #pragma unroll
    for (int r = 0; r < 4; ++r) {
      size_t p = ((size_t)b*1024 + tt + q*4 + r)*256 + o;
      float m = sigf(acc[i][r] + bl);
      est[p] = f2bf(m * bf2f(est[p]));
    }
  }
}

// ---------------- decoder GEMM: dec[b,f,t] = sum_o est[b,t,o] Wdec[f,o] -----
__global__ __launch_bounds__(256) void k_dec(const unsigned short* __restrict__ est,
    const unsigned short* __restrict__ wdecb, float* __restrict__ dec) {
  const int bx = blockIdx.x;                   // 64 * 8 * 16
  const int b = bx >> 7, rem = bx & 127, fy = rem >> 4, tx = rem & 15;
  const int f0 = fy*64, t0 = tx*64;
  const int tid = threadIdx.x, w = tid >> 6, lane = tid & 63;
  const int n16 = lane & 15, q = lane >> 4;
  f32x4 acc[4];
  #pragma unroll
  for (int i = 0; i < 4; ++i) acc[i] = (f32x4){0.f,0.f,0.f,0.f};
  const int fr = f0 + w*16 + n16;
  for (int ks = 0; ks < 8; ++ks) {
    int k0 = ks*32 + q*8;
    bf16x8 af = *(const bf16x8*)&wdecb[(size_t)fr*256 + k0];
    #pragma unroll
    for (int i = 0; i < 4; ++i) {
      int trow = t0 + i*16 + n16;
      bf16x8 bf = *(const bf16x8*)&est[((size_t)b*1024 + trow)*256 + k0];
      acc[i] = __builtin_amdgcn_mfma_f32_16x16x32_bf16(af, bf, acc[i], 0,0,0);
    }
  }
  #pragma unroll
  for (int i = 0; i < 4; ++i) {
    int tcol = t0 + i*16 + n16;
    #pragma unroll
    for (int r = 0; r < 4; ++r) {
      int f = f0 + w*16 + q*4 + r;
      dec[((size_t)b*512 + f)*1024 + tcol] = acc[i][r];
    }
  }
}

extern "C" void kernel_launch(void* const* d_in, const int* in_sizes, int n_in,
                              void* d_out, int out_size, void* d_ws, size_t ws_size,
                              hipStream_t stream) {
  (void)in_sizes; (void)n_in; (void)out_size; (void)ws_size;
  const float* x      = (const float*)d_in[0];
  const float* states = (const float*)d_in[1];
  const float* Wenc   = (const float*)d_in[2];
  const float* lng    = (const float*)d_in[3];
  const float* lnb    = (const float*)d_in[4];
  const float* Wih1   = (const float*)d_in[5];
  const float* Whh1   = (const float*)d_in[6];
  const float* bih1   = (const float*)d_in[7];
  const float* bhh1   = (const float*)d_in[8];
  const float* Wih2   = (const float*)d_in[9];
  const float* Whh2   = (const float*)d_in[10];
  const float* bih2   = (const float*)d_in[11];
  const float* bhh2   = (const float*)d_in[12];
  const float* Wlin   = (const float*)d_in[13];
  const float* blin   = (const float*)d_in[14];
  const float* Wdec   = (const float*)d_in[15];

  float* dec = (float*)d_out;
  float* out_states = dec + DEC_ELEMS;

  char* ws = (char*)d_ws;
  unsigned short* enc_norm = (unsigned short*)ws; ws += (size_t)B_*T_*E_*2;   // 32 MB
  unsigned short* encoded  = (unsigned short*)ws; ws += (size_t)B_*T_*E_*2;   // 32 MB (est in place)
  unsigned short* x2buf    = (unsigned short*)ws; ws += (size_t)B_*T_*H_*2;   // 64 MB
  unsigned short* wencb    = (unsigned short*)ws; ws += 131072*2;
  unsigned short* wlinb    = (unsigned short*)ws; ws += 131072*2;
  unsigned short* wdecb    = (unsigned short*)ws; ws += 131072*2;
  unsigned short* h1bc     = (unsigned short*)ws; ws += 2*BH_*2;
  unsigned short* h2bc     = (unsigned short*)ws; ws += 2*BH_*2;
  int* cnts                = (int*)ws;            ws += 2*4*T_*4;

  (void)hipMemsetAsync(cnts, 0, 2*4*T_*4, stream);
  k_prep<<<512, 256, 0, stream>>>(Wenc, Wlin, Wdec, wencb, wlinb, wdecb);
  k_enc<<<4096, 256, 0, stream>>>(x, wencb, lng, lnb, enc_norm, encoded);
  k_recur<<<256, 256, 0, stream>>>(states, Wih1, Whh1, bih1, bhh1,
                                   Wih2, Whh2, bih2, bhh2,
                                   enc_norm, x2buf, h1bc, h2bc,
                                   cnts, cnts + 4*T_, out_states);
  k_mask<<<4096, 256, 0, stream>>>(x2buf, wlinb, blin, encoded);
  k_dec<<<8192, 256, 0, stream>>>(encoded, wdecb, dec);
}